// Round 10
// baseline (254.100 us; speedup 1.0000x reference)
//
#include <hip/hip_runtime.h>
#include <hip/hip_bf16.h>

typedef __hip_bfloat16 bf16;
typedef __attribute__((ext_vector_type(8))) short short8;   // 8 bf16 = one MFMA A/B frag
typedef __attribute__((ext_vector_type(4))) float f32x4;    // MFMA C/D frag

#define MFMA(a, b, c) __builtin_amdgcn_mfma_f32_16x16x32_bf16(a, b, c, 0, 0, 0)

static __device__ __forceinline__ float b2f(unsigned short u) {
  union { unsigned u; float f; } t; t.u = ((unsigned)u) << 16; return t.f;
}
static __device__ __forceinline__ unsigned short f2bf(float f) {
  union { float f; unsigned u; } t; t.f = f;
  unsigned r = t.u + 0x7fffu + ((t.u >> 16) & 1u);   // RNE
  return (unsigned short)(r >> 16);
}
static __device__ __forceinline__ unsigned pack2(float a, float b) {
  return (unsigned)f2bf(a) | ((unsigned)f2bf(b) << 16);
}
// packed f32x2 -> bf16x2 (RNE); lo -> low 16 bits.
static __device__ __forceinline__ unsigned pack_bf2(float lo, float hi) {
  __hip_bfloat162 h = __float22bfloat162_rn(float2{lo, hi});
  union { __hip_bfloat162 h; unsigned u; } c; c.h = h; return c.u;
}

// Direct global->LDS staging (guide m97: width 16).
#if defined(__has_builtin)
#if __has_builtin(__builtin_amdgcn_global_load_lds)
#define HAVE_GLL 1
#endif
#endif
#ifdef HAVE_GLL
#define LOADLDS(g, p) __builtin_amdgcn_global_load_lds( \
    (const __attribute__((address_space(1))) void*)(g), \
    (__attribute__((address_space(3))) void*)(p), 16, 0, 0)
#else
#define LOADLDS(g, p) do { uint4 t_ = *(const uint4*)(g); \
    *(uint4*)((char*)(p) + (threadIdx.x & 63) * 16) = t_; } while (0)
#endif

// ---- workspace layout (bf16 element offsets). d_ws is 256 MiB; we use ~38 MB ----
#define KB_OFF   ((size_t)0)          // K  [2048][1024]
#define QB_OFF   ((size_t)2097152)    // Q  [2048][1024]
#define G1_OFF   ((size_t)4194304)    // G1 [2048][1024]
#define G2_OFF   ((size_t)6291456)    // G2 [2048][1024]
#define VT_OFF   ((size_t)8388608)    // V^T [512][2048]
#define WT_BASE  ((size_t)9437184)
#define WTK_OFF  (WT_BASE)                       // [1024][512]
#define WTQ_OFF  (WT_BASE + (size_t)524288)
#define WTG1_OFF (WT_BASE + (size_t)1048576)
#define WTG2_OFF (WT_BASE + (size_t)1572864)
#define WTV_OFF  (WT_BASE + (size_t)2097152)     // [512][512]
// After proj, the WT region is dead -> reuse for attention partials:
#define NUM0_OFF (WT_BASE)                       // bf16 [2048][512] (n-split 0)
#define NUM1_OFF (WT_BASE + (size_t)1048576)     // bf16 [2048][512] (n-split 1)
#define NUM2_OFF ((size_t)11796480)              // bf16 [2048][512] (n-split 2)
#define NUM3_OFF ((size_t)12845056)              // bf16 [2048][512] (n-split 3)
#define DEN_OFF  ((size_t)13893632)              // f32  [4][8][2048] (raw bytes)
#define VSUM_OFF ((size_t)14024704)              // f32  [4][8][64] per-split V col-sums
// bf16 copies of the X activations (written by prep, read by proj):
#define XFA_OFF  ((size_t)14680064)              // bf16 [2048][512] first_app
#define XSA_OFF  ((size_t)15728640)              // bf16 [2048][512] second_app
#define XFP_OFF  ((size_t)16777216)              // bf16 [2048][512] first_pos
#define XSP_OFF  ((size_t)17825792)              // bf16 [2048][512] second_pos

// LDS XOR swizzles (byte-address based, applied identically on write & read)
#define KSWZ(r, cB)  ((((r) * 256) + (cB)) ^ ((((r) & 7)) << 4))   // [64][128] bf16 tiles
#define PS2WZ(r, cB) ((((r) * 128) + (cB)) ^ ((((r) & 7)) << 4))   // [128][64] bf16 tile
#define VSWZ(r, cB)  ((((r) * 128) + (cB)) ^ ((((r) & 7)) << 4))   // [64][64] bf16 tile

// prep: z 0-4 = transpose+convert W fp32 -> Wt bf16; z 5-8 = X fp32 -> bf16.
__global__ __launch_bounds__(256)
void prep_kernel(const float* __restrict__ WK, const float* __restrict__ WQ,
                 const float* __restrict__ WG1, const float* __restrict__ WG2,
                 const float* __restrict__ WV,
                 const float* __restrict__ fa, const float* __restrict__ fp,
                 const float* __restrict__ sa, const float* __restrict__ sp,
                 bf16* __restrict__ ws)
{
  const int z = blockIdx.z;
  const int tid = threadIdx.x;
  if (z >= 5) {  // ---- xconv ----
    const float* src; size_t doff;
    switch (z) {
      case 5:  src = fa; doff = XFA_OFF; break;
      case 6:  src = sa; doff = XSA_OFF; break;
      case 7:  src = fp; doff = XFP_OFF; break;
      default: src = sp; doff = XSP_OFF; break;
    }
    const size_t e = ((size_t)(blockIdx.y * 32 + blockIdx.x) * 256 + tid) * 8;
    float4 a = *(const float4*)(src + e);
    float4 b = *(const float4*)(src + e + 4);
    uint4 o;
    o.x = pack2(a.x, a.y); o.y = pack2(a.z, a.w);
    o.z = pack2(b.x, b.y); o.w = pack2(b.z, b.w);
    *(uint4*)(ws + doff + e) = o;
    return;
  }
  // ---- wtrans ----
  __shared__ float T[32][33];
  const float* W; unsigned short* Wt; int N;
  switch (z) {
    case 0:  W = WK;  Wt = (unsigned short*)(ws + WTK_OFF);  N = 1024; break;
    case 1:  W = WQ;  Wt = (unsigned short*)(ws + WTQ_OFF);  N = 1024; break;
    case 2:  W = WG1; Wt = (unsigned short*)(ws + WTG1_OFF); N = 1024; break;
    case 3:  W = WG2; Wt = (unsigned short*)(ws + WTG2_OFF); N = 1024; break;
    default: W = WV;  Wt = (unsigned short*)(ws + WTV_OFF);  N = 512;  break;
  }
  int n0 = blockIdx.x * 32, k0 = blockIdx.y * 32;
  if (n0 >= N) return;
  int kk = tid >> 3, nn = (tid & 7) * 4;
  float4 v = *(const float4*)(W + (size_t)(k0 + kk) * N + n0 + nn);
  T[kk][nn] = v.x; T[kk][nn + 1] = v.y; T[kk][nn + 2] = v.z; T[kk][nn + 3] = v.w;
  __syncthreads();
  int n2 = tid >> 3, k2 = (tid & 7) * 4;
  uint2 pw;
  pw.x = pack2(T[k2][n2],     T[k2 + 1][n2]);
  pw.y = pack2(T[k2 + 2][n2], T[k2 + 3][n2]);
  *(uint2*)(Wt + (size_t)(n0 + n2) * 512 + k0 + k2) = pw;
}

// Batched MFMA projection GEMM v2 (m97 structure, verified round 8).
__global__ __launch_bounds__(256)
void proj_mfma_kernel(const float* __restrict__ bKp, const float* __restrict__ bQp,
                      const float* __restrict__ bG1p, const float* __restrict__ bG2p,
                      const float* __restrict__ bVp, bf16* __restrict__ ws)
{
  __shared__ short As[128][64];
  __shared__ short Bs[128][64];
  const bf16* X; const bf16* Wt; const float* bias; unsigned short* C;
  int N; bool trans = false;
  switch (blockIdx.z) {
    case 0:  X = ws + XFA_OFF; Wt = ws + WTK_OFF;  bias = bKp;  C = (unsigned short*)(ws + KB_OFF); N = 1024; break;
    case 1:  X = ws + XSA_OFF; Wt = ws + WTQ_OFF;  bias = bQp;  C = (unsigned short*)(ws + QB_OFF); N = 1024; break;
    case 2:  X = ws + XFP_OFF; Wt = ws + WTG1_OFF; bias = bG1p; C = (unsigned short*)(ws + G1_OFF); N = 1024; break;
    case 3:  X = ws + XSP_OFF; Wt = ws + WTG2_OFF; bias = bG2p; C = (unsigned short*)(ws + G2_OFF); N = 1024; break;
    default: X = ws + XFA_OFF; Wt = ws + WTV_OFF;  bias = bVp;  C = (unsigned short*)(ws + VT_OFF); N = 512; trans = true; break;
  }
  const int n0 = blockIdx.x * 128;
  if (n0 >= N) return;
  const int m0 = blockIdx.y * 128;
  const int tid = threadIdx.x;
  const int w = tid >> 6, l = tid & 63, l15 = l & 15, l4 = l >> 4;
  const int wm = (w & 1) * 64, wn = (w >> 1) * 64;

  const int lr = l >> 3;
  const int cp = (l & 7) ^ lr;
  const bf16* gA = X  + (size_t)(m0 + w * 32 + lr) * 512 + cp * 8;
  const bf16* gB = Wt + (size_t)(n0 + w * 32 + lr) * 512 + cp * 8;
  char* const ldsA = (char*)&As[0][0] + w * 32 * 128;
  char* const ldsB = (char*)&Bs[0][0] + w * 32 * 128;

  const f32x4 zero = {0.f, 0.f, 0.f, 0.f};
  f32x4 acc[4][4];
#pragma unroll
  for (int i = 0; i < 4; ++i)
#pragma unroll
    for (int j = 0; j < 4; ++j) acc[i][j] = zero;

  const int swz = (l15 & 7) << 4;   // read-side XOR (row&7 == l15&7 here)

  for (int kc = 0; kc < 512; kc += 64) {
    __syncthreads();
#pragma unroll
    for (int i = 0; i < 4; ++i) {
      LOADLDS(gA + (size_t)i * 8 * 512 + kc, ldsA + i * 1024);
      LOADLDS(gB + (size_t)i * 8 * 512 + kc, ldsB + i * 1024);
    }
    __syncthreads();

#pragma unroll
    for (int kk = 0; kk < 2; ++kk) {
      short8 xf[4], wf[4];
#pragma unroll
      for (int t = 0; t < 4; ++t) {
        xf[t] = *(const short8*)((char*)&As[0][0] + (wm + t * 16 + l15) * 128
                                  + ((kk * 64 + l4 * 16) ^ swz));
        wf[t] = *(const short8*)((char*)&Bs[0][0] + (wn + t * 16 + l15) * 128
                                  + ((kk * 64 + l4 * 16) ^ swz));
      }
      if (!trans) {
#pragma unroll
        for (int i = 0; i < 4; ++i)
#pragma unroll
          for (int j = 0; j < 4; ++j)
            acc[i][j] = MFMA(wf[i], xf[j], acc[i][j]);   // D[n][m]
      } else {
#pragma unroll
        for (int i = 0; i < 4; ++i)
#pragma unroll
          for (int j = 0; j < 4; ++j)
            acc[i][j] = MFMA(xf[i], wf[j], acc[i][j]);   // D[m][n]
      }
    }
  }

  if (!trans) {
#pragma unroll
    for (int tn = 0; tn < 4; ++tn) {
      float4 b4 = *(const float4*)(bias + n0 + wn + tn * 16 + l4 * 4);
#pragma unroll
      for (int tm = 0; tm < 4; ++tm) {
        uint2 pw;
        pw.x = pack2(acc[tn][tm][0] + b4.x, acc[tn][tm][1] + b4.y);
        pw.y = pack2(acc[tn][tm][2] + b4.z, acc[tn][tm][3] + b4.w);
        *(uint2*)(C + (size_t)(m0 + wm + tm * 16 + l15) * N + n0 + wn + tn * 16 + l4 * 4) = pw;
      }
    }
  } else {
#pragma unroll
    for (int tn = 0; tn < 4; ++tn) {
      float bn = bias[n0 + wn + tn * 16 + l15];
#pragma unroll
      for (int tm = 0; tm < 4; ++tm) {
        uint2 pw;
        pw.x = pack2(acc[tm][tn][0] + bn, acc[tm][tn][1] + bn);
        pw.y = pack2(acc[tm][tn][2] + bn, acc[tm][tn][3] + bn);
        *(uint2*)(C + (size_t)(n0 + wn + tn * 16 + l15) * 2048 + m0 + wm + tm * 16 + l4 * 4) = pw;
      }
    }
  }
}

// MFMA fused attention, 8-wave blocks with n-half score redistribution.
// r9 accounting: LDS pipe ~67% busy (50K traffic + 22K conflict cyc of 107K),
// dominated by score-phase K/G1 frag reads (262KB of 400KB/block-iter) -- all
// 8 waves redundantly read the full tiles. Now: wave w = (m-pair p=w>>1,
// n-half nh=w&1) computes S[32 n-rows][2 m-subs]: score reads HALVE (32->16
// frags/wave-iter), MFMA count unchanged, Q/G2 regs +32 (fits 128 cap ->
// still 2 blocks/CU). P crosses waves via [128][64] swizzled LDS (16KB, same
// as old Ps) with one extra barrier; PV: wave w owns m-sub w (full P row).
// Denominator: VALU-sum of pf registers in PV (ones-MFMA dropped).
__global__ __launch_bounds__(512, 4)
void attn_mfma_kernel(const bf16* __restrict__ Kb, const bf16* __restrict__ G1b,
                      const bf16* __restrict__ Vtg, const bf16* __restrict__ Qb,
                      const bf16* __restrict__ G2b, bf16* __restrict__ ws)
{
  __shared__ short Ks[64][128];
  __shared__ short G1s[64][128];
  __shared__ short Vts[64][64];
  __shared__ short Ps2[128][64];

  const int tid = threadIdx.x;
  const int w   = tid >> 6;        // 0..7
  const int p   = w >> 1;          // m-sub pair (subs 2p, 2p+1)
  const int nh  = w & 1;           // n-half for score phase
  const int l   = tid & 63;
  const int l15 = l & 15;
  const int l4  = l >> 4;

  // XCD-aware remap: grid (16,8,4) -> f in [0,512); f%8 = XCD.
  const int f = blockIdx.x + blockIdx.y * 16 + blockIdx.z * 128;
  const int vid = (f & 7) * 64 + (f >> 3);
  const int m0    = (vid & 15) * 128;
  const int grp   = vid >> 4;      // 0..31
  const int h     = grp >> 2;
  const int split = grp & 3;

  // Q/G2 B-frags for the wave's TWO m-subs (rows p*32+l15 and p*32+16+l15).
  short8 qf0[4], gf0[4], qf1[4], gf1[4];
  {
    const size_t ro0 = (size_t)(m0 + p * 32 + l15) * 1024 + h * 128 + l4 * 8;
#pragma unroll
    for (int kk = 0; kk < 4; ++kk) {
      qf0[kk] = *(const short8*)(Qb + ro0 + kk * 32);
      gf0[kk] = *(const short8*)(G2b + ro0 + kk * 32);
    }
    const size_t ro1 = ro0 + 16 * 1024;
#pragma unroll
    for (int kk = 0; kk < 4; ++kk) {
      qf1[kk] = *(const short8*)(Qb + ro1 + kk * 32);
      gf1[kk] = *(const short8*)(G2b + ro1 + kk * 32);
    }
  }
  float sc0, sc1;
  {
    float sq = 0.f, sg = 0.f;
#pragma unroll
    for (int kk = 0; kk < 4; ++kk)
#pragma unroll
      for (int j = 0; j < 8; ++j) {
        float q = b2f((unsigned short)qf0[kk][j]);
        float g = b2f((unsigned short)gf0[kk][j]);
        sq += q * q; sg += g * g;
      }
    sq += __shfl_xor(sq, 16, 64); sq += __shfl_xor(sq, 32, 64);
    sg += __shfl_xor(sg, 16, 64); sg += __shfl_xor(sg, 32, 64);
    sc0 = rsqrtf(sq) * rsqrtf(sg) * (1.0f / 16384.0f);
  }
  {
    float sq = 0.f, sg = 0.f;
#pragma unroll
    for (int kk = 0; kk < 4; ++kk)
#pragma unroll
      for (int j = 0; j < 8; ++j) {
        float q = b2f((unsigned short)qf1[kk][j]);
        float g = b2f((unsigned short)gf1[kk][j]);
        sq += q * q; sg += g * g;
      }
    sq += __shfl_xor(sq, 16, 64); sq += __shfl_xor(sq, 32, 64);
    sg += __shfl_xor(sg, 16, 64); sg += __shfl_xor(sg, 32, 64);
    sc1 = rsqrtf(sq) * rsqrtf(sg) * (1.0f / 16384.0f);
  }

  // staging: 512 threads cover each tile exactly once (same as r9).
  const int r0  = tid >> 3;          // 0..63  K/G row
  const int c0  = (tid & 7) * 16;    // shorts
  const int c0b = c0 * 2;            // bytes
  const int jv  = tid >> 3;          // 0..63  V row (dv)
  const int nv  = (tid & 7) * 8;     // shorts
  const int nvB = nv * 2;            // bytes

  short8 pk0, pk1, pg0, pg1, pv0;
  auto load_tile = [&](int nt) {     // nt in global 64-units
    const int n0 = nt * 64;
    const bf16* kp = Kb  + (size_t)(n0 + r0) * 1024 + h * 128 + c0;
    const bf16* gp = G1b + (size_t)(n0 + r0) * 1024 + h * 128 + c0;
    pk0 = *(const short8*)(kp);
    pk1 = *(const short8*)(kp + 8);
    pg0 = *(const short8*)(gp);
    pg1 = *(const short8*)(gp + 8);
    const bf16* vp = Vtg + (size_t)(h * 64 + jv) * 2048 + n0 + nv;
    pv0 = *(const short8*)(vp);
  };
  const int ntbase = split * 8;
  load_tile(ntbase);

  const f32x4 zero = {0.f, 0.f, 0.f, 0.f};
  f32x4 accO[4];
#pragma unroll
  for (int t = 0; t < 4; ++t) accO[t] = zero;
  float dacc = 0.f;
  float vsum_part = 0.f;

  char* const ksb = (char*)&Ks[0][0];
  char* const g1p = (char*)&G1s[0][0];
  char* const vsb = (char*)&Vts[0][0];
  char* const ps2 = (char*)&Ps2[0][0];

  for (int nt = 0; nt < 8; ++nt) {
    __syncthreads();                 // B1: prev iter's PV reads done
    *(short8*)(ksb + KSWZ(r0, c0b))      = pk0;
    *(short8*)(ksb + KSWZ(r0, c0b + 16)) = pk1;
    *(short8*)(g1p + KSWZ(r0, c0b))      = pg0;
    *(short8*)(g1p + KSWZ(r0, c0b + 16)) = pg1;
    *(short8*)(vsb + VSWZ(jv, nvB))      = pv0;
#pragma unroll
    for (int j = 0; j < 8; ++j)          // V col-sum partial (this split's n)
      vsum_part += b2f((unsigned short)pv0[j]);
    __syncthreads();                 // B2: staged data visible
    if (nt + 1 < 8) load_tile(ntbase + nt + 1);

    // ---- scores: wave's n-half (rows nh*32..nh*32+31) x its 2 m-subs ----
#pragma unroll
    for (int t = 0; t < 2; ++t) {
      const int nrow = nh * 32 + t * 16 + l15;
      f32x4 sa0 = zero, sg0v = zero, sa1 = zero, sg1v = zero;
      __builtin_amdgcn_s_setprio(1);
#pragma unroll
      for (int kk = 0; kk < 4; ++kk) {
        short8 kbf = *(const short8*)(ksb + KSWZ(nrow, kk * 64 + l4 * 16));
        sa0 = MFMA(kbf, qf0[kk], sa0);
        sa1 = MFMA(kbf, qf1[kk], sa1);
        short8 gbf = *(const short8*)(g1p + KSWZ(nrow, kk * 64 + l4 * 16));
        sg0v = MFMA(gbf, gf0[kk], sg0v);
        sg1v = MFMA(gbf, gf1[kk], sg1v);
      }
      __builtin_amdgcn_s_setprio(0);
      // P' = exp(x)-1 ~= x + x^2/2 (|x| ~ 1e-4); lane holds 4 n's of one m-row
      {
        float x0 = sa0[0] * sg0v[0] * sc0;
        float x1 = sa0[1] * sg0v[1] * sc0;
        float x2 = sa0[2] * sg0v[2] * sc0;
        float x3 = sa0[3] * sg0v[3] * sc0;
        float p0 = __builtin_fmaf(0.5f * x0, x0, x0);
        float p1 = __builtin_fmaf(0.5f * x1, x1, x1);
        float p2 = __builtin_fmaf(0.5f * x2, x2, x2);
        float p3 = __builtin_fmaf(0.5f * x3, x3, x3);
        uint2 pw;
        pw.x = pack_bf2(p0, p1);
        pw.y = pack_bf2(p2, p3);
        *(uint2*)(ps2 + PS2WZ(p * 32 + l15, (nh * 2 + t) * 32 + l4 * 8)) = pw;
      }
      {
        float x0 = sa1[0] * sg1v[0] * sc1;
        float x1 = sa1[1] * sg1v[1] * sc1;
        float x2 = sa1[2] * sg1v[2] * sc1;
        float x3 = sa1[3] * sg1v[3] * sc1;
        float p0 = __builtin_fmaf(0.5f * x0, x0, x0);
        float p1 = __builtin_fmaf(0.5f * x1, x1, x1);
        float p2 = __builtin_fmaf(0.5f * x2, x2, x2);
        float p3 = __builtin_fmaf(0.5f * x3, x3, x3);
        uint2 pw;
        pw.x = pack_bf2(p0, p1);
        pw.y = pack_bf2(p2, p3);
        *(uint2*)(ps2 + PS2WZ(p * 32 + 16 + l15, (nh * 2 + t) * 32 + l4 * 8)) = pw;
      }
    }
    __syncthreads();                 // B3: full P tile visible

    // ---- PV: wave w owns m-sub w (rows w*16..w*16+15), all 64 n ----
#pragma unroll
    for (int ks = 0; ks < 2; ++ks) {
      short8 pf = *(const short8*)(ps2 + PS2WZ(w * 16 + l15, ks * 64 + l4 * 16));
#pragma unroll
      for (int j = 0; j < 8; ++j)        // denominator partial (row w*16+l15)
        dacc += b2f((unsigned short)pf[j]);
      __builtin_amdgcn_s_setprio(1);
#pragma unroll
      for (int jt = 0; jt < 4; ++jt) {
        short8 vbf = *(const short8*)(vsb + VSWZ(jt * 16 + l15, ks * 64 + l4 * 16));
        accO[jt] = MFMA(pf, vbf, accO[jt]);
      }
      __builtin_amdgcn_s_setprio(0);
    }
  }

  // ---- vsum reduce: 8 consecutive lanes (same jv) hold quarters of row jv ----
  vsum_part += __shfl_xor(vsum_part, 1, 64);
  vsum_part += __shfl_xor(vsum_part, 2, 64);
  vsum_part += __shfl_xor(vsum_part, 4, 64);
  if ((vid & 15) == 0 && (tid & 7) == 0)
    ((float*)(ws + VSUM_OFF))[(size_t)(split * 8 + h) * 64 + jv] = vsum_part;

  // ---- denominator reduce over the 4 l4-groups of each m-row ----
  dacc += __shfl_xor(dacc, 16, 64);
  dacc += __shfl_xor(dacc, 32, 64);

  // ---- write partials ----
  size_t noff;
  switch (split) {
    case 0:  noff = NUM0_OFF; break;
    case 1:  noff = NUM1_OFF; break;
    case 2:  noff = NUM2_OFF; break;
    default: noff = NUM3_OFF; break;
  }
  bf16* num = ws + noff;
  float* den = (float*)(ws + DEN_OFF);
  if (l4 == 0)
    den[(size_t)(split * 8 + h) * 2048 + m0 + w * 16 + l15] = dacc;
#pragma unroll
  for (int jt = 0; jt < 4; ++jt) {
#pragma unroll
    for (int r = 0; r < 4; ++r)
      num[(size_t)(m0 + w * 16 + l4 * 4 + r) * 512 + h * 64 + jt * 16 + l15]
        = __float2bfloat16(accO[jt][r]);
  }
}

// out[m][c] = (num0..3 + Vsum[c]) / (2048 + den0..3), 8 elems/thread
__global__ __launch_bounds__(256)
void combine_kernel(const bf16* __restrict__ ws, float* __restrict__ out)
{
  const unsigned short* num0 = (const unsigned short*)(ws + NUM0_OFF);
  const unsigned short* num1 = (const unsigned short*)(ws + NUM1_OFF);
  const unsigned short* num2 = (const unsigned short*)(ws + NUM2_OFF);
  const unsigned short* num3 = (const unsigned short*)(ws + NUM3_OFF);
  const float* den  = (const float*)(ws + DEN_OFF);
  const float* vsum = (const float*)(ws + VSUM_OFF);   // f32 [4][8][64]
  int idx = (blockIdx.x * 256 + threadIdx.x) * 8;
  int m = idx >> 9, c = idx & 511, h = c >> 6, c64 = c & 63;
  float d = 2048.0f + den[(size_t)h * 2048 + m] + den[(size_t)(8 + h) * 2048 + m]
                    + den[(size_t)(16 + h) * 2048 + m] + den[(size_t)(24 + h) * 2048 + m];
  float rd = 1.0f / d;
  short8 a = *(const short8*)(num0 + idx);
  short8 b = *(const short8*)(num1 + idx);
  short8 e = *(const short8*)(num2 + idx);
  short8 g = *(const short8*)(num3 + idx);
  float vs[8] = {0.f, 0.f, 0.f, 0.f, 0.f, 0.f, 0.f, 0.f};
#pragma unroll
  for (int s = 0; s < 4; ++s) {
    float4 v0 = *(const float4*)(vsum + (size_t)(s * 8 + h) * 64 + c64);
    float4 v1 = *(const float4*)(vsum + (size_t)(s * 8 + h) * 64 + c64 + 4);
    vs[0] += v0.x; vs[1] += v0.y; vs[2] += v0.z; vs[3] += v0.w;
    vs[4] += v1.x; vs[5] += v1.y; vs[6] += v1.z; vs[7] += v1.w;
  }
  float r[8];
#pragma unroll
  for (int j = 0; j < 8; ++j)
    r[j] = (b2f((unsigned short)a[j]) + b2f((unsigned short)b[j])
          + b2f((unsigned short)e[j]) + b2f((unsigned short)g[j]) + vs[j]) * rd;
  *(float4*)(out + idx)     = float4{r[0], r[1], r[2], r[3]};
  *(float4*)(out + idx + 4) = float4{r[4], r[5], r[6], r[7]};
}

extern "C" void kernel_launch(void* const* d_in, const int* in_sizes, int n_in,
                              void* d_out, int out_size, void* d_ws, size_t ws_size,
                              hipStream_t stream) {
  const float* first_app  = (const float*)d_in[0];
  const float* first_pos  = (const float*)d_in[1];
  const float* second_app = (const float*)d_in[2];
  const float* second_pos = (const float*)d_in[3];
  const float* WK  = (const float*)d_in[4];
  const float* bK  = (const float*)d_in[5];
  const float* WQ  = (const float*)d_in[6];
  const float* bQ  = (const float*)d_in[7];
  const float* WV  = (const float*)d_in[8];
  const float* bV  = (const float*)d_in[9];
  const float* WG1 = (const float*)d_in[10];
  const float* bG1 = (const float*)d_in[11];
  const float* WG2 = (const float*)d_in[12];
  const float* bG2 = (const float*)d_in[13];

  bf16* ws = (bf16*)d_ws;

  prep_kernel<<<dim3(32, 16, 9), 256, 0, stream>>>(
      WK, WQ, WG1, WG2, WV, first_app, first_pos, second_app, second_pos, ws);
  proj_mfma_kernel<<<dim3(8, 16, 5), 256, 0, stream>>>(bK, bQ, bG1, bG2, bV, ws);
  attn_mfma_kernel<<<dim3(16, 8, 4), 512, 0, stream>>>(
      ws + KB_OFF, ws + G1_OFF, ws + VT_OFF, ws + QB_OFF, ws + G2_OFF, ws);
  combine_kernel<<<dim3(512), 256, 0, stream>>>(ws, (float*)d_out);
}

// Round 11
// 158.829 us; speedup vs baseline: 1.5998x; 1.5998x over previous
//
#include <hip/hip_runtime.h>
#include <hip/hip_bf16.h>

typedef __hip_bfloat16 bf16;
typedef __attribute__((ext_vector_type(8))) short short8;   // 8 bf16 = one MFMA A/B frag
typedef __attribute__((ext_vector_type(4))) float f32x4;    // MFMA C/D frag

#define MFMA(a, b, c) __builtin_amdgcn_mfma_f32_16x16x32_bf16(a, b, c, 0, 0, 0)

static __device__ __forceinline__ float b2f(unsigned short u) {
  union { unsigned u; float f; } t; t.u = ((unsigned)u) << 16; return t.f;
}
static __device__ __forceinline__ unsigned short f2bf(float f) {
  union { float f; unsigned u; } t; t.f = f;
  unsigned r = t.u + 0x7fffu + ((t.u >> 16) & 1u);   // RNE
  return (unsigned short)(r >> 16);
}
static __device__ __forceinline__ unsigned pack2(float a, float b) {
  return (unsigned)f2bf(a) | ((unsigned)f2bf(b) << 16);
}
// packed f32x2 -> bf16x2 (RNE); lo -> low 16 bits.
static __device__ __forceinline__ unsigned pack_bf2(float lo, float hi) {
  __hip_bfloat162 h = __float22bfloat162_rn(float2{lo, hi});
  union { __hip_bfloat162 h; unsigned u; } c; c.h = h; return c.u;
}

// Direct global->LDS staging (guide m97: width 16).
#if defined(__has_builtin)
#if __has_builtin(__builtin_amdgcn_global_load_lds)
#define HAVE_GLL 1
#endif
#endif
#ifdef HAVE_GLL
#define LOADLDS(g, p) __builtin_amdgcn_global_load_lds( \
    (const __attribute__((address_space(1))) void*)(g), \
    (__attribute__((address_space(3))) void*)(p), 16, 0, 0)
#else
#define LOADLDS(g, p) do { uint4 t_ = *(const uint4*)(g); \
    *(uint4*)((char*)(p) + (threadIdx.x & 63) * 16) = t_; } while (0)
#endif

// ---- workspace layout (bf16 element offsets). d_ws is 256 MiB; we use ~38 MB ----
#define KB_OFF   ((size_t)0)          // K  [2048][1024]
#define QB_OFF   ((size_t)2097152)    // Q  [2048][1024]
#define G1_OFF   ((size_t)4194304)    // G1 [2048][1024]
#define G2_OFF   ((size_t)6291456)    // G2 [2048][1024]
#define VT_OFF   ((size_t)8388608)    // V^T [512][2048]
#define WT_BASE  ((size_t)9437184)
#define WTK_OFF  (WT_BASE)                       // [1024][512]
#define WTQ_OFF  (WT_BASE + (size_t)524288)
#define WTG1_OFF (WT_BASE + (size_t)1048576)
#define WTG2_OFF (WT_BASE + (size_t)1572864)
#define WTV_OFF  (WT_BASE + (size_t)2097152)     // [512][512]
// After proj, the WT region is dead -> reuse for attention partials:
#define NUM0_OFF (WT_BASE)                       // bf16 [2048][512] (n-split 0)
#define NUM1_OFF (WT_BASE + (size_t)1048576)     // bf16 [2048][512] (n-split 1)
#define NUM2_OFF ((size_t)11796480)              // bf16 [2048][512] (n-split 2)
#define NUM3_OFF ((size_t)12845056)              // bf16 [2048][512] (n-split 3)
#define DEN_OFF  ((size_t)13893632)              // f32  [4][8][2048] (raw bytes)
#define VSUM_OFF ((size_t)14024704)              // f32  [4][8][64] per-split V col-sums
// bf16 copies of the X activations (written by prep, read by proj):
#define XFA_OFF  ((size_t)14680064)              // bf16 [2048][512] first_app
#define XSA_OFF  ((size_t)15728640)              // bf16 [2048][512] second_app
#define XFP_OFF  ((size_t)16777216)              // bf16 [2048][512] first_pos
#define XSP_OFF  ((size_t)17825792)              // bf16 [2048][512] second_pos

// LDS XOR swizzles (byte-address based, applied identically on write & read)
#define KSWZ(r, cB) ((((r) * 256) + (cB)) ^ ((((r) & 7)) << 4))   // [64][128] bf16 tiles
#define PSWZ(r, cB) ((((r) * 128) + (cB)) ^ ((((r) & 7)) << 4))   // [16][64] bf16 tile
#define VSWZ(r, cB) ((((r) * 128) + (cB)) ^ ((((r) & 7)) << 4))   // [64][64] bf16 tile

// prep: z 0-4 = transpose+convert W fp32 -> Wt bf16; z 5-8 = X fp32 -> bf16.
__global__ __launch_bounds__(256)
void prep_kernel(const float* __restrict__ WK, const float* __restrict__ WQ,
                 const float* __restrict__ WG1, const float* __restrict__ WG2,
                 const float* __restrict__ WV,
                 const float* __restrict__ fa, const float* __restrict__ fp,
                 const float* __restrict__ sa, const float* __restrict__ sp,
                 bf16* __restrict__ ws)
{
  const int z = blockIdx.z;
  const int tid = threadIdx.x;
  if (z >= 5) {  // ---- xconv ----
    const float* src; size_t doff;
    switch (z) {
      case 5:  src = fa; doff = XFA_OFF; break;
      case 6:  src = sa; doff = XSA_OFF; break;
      case 7:  src = fp; doff = XFP_OFF; break;
      default: src = sp; doff = XSP_OFF; break;
    }
    const size_t e = ((size_t)(blockIdx.y * 32 + blockIdx.x) * 256 + tid) * 8;
    float4 a = *(const float4*)(src + e);
    float4 b = *(const float4*)(src + e + 4);
    uint4 o;
    o.x = pack2(a.x, a.y); o.y = pack2(a.z, a.w);
    o.z = pack2(b.x, b.y); o.w = pack2(b.z, b.w);
    *(uint4*)(ws + doff + e) = o;
    return;
  }
  // ---- wtrans ----
  __shared__ float T[32][33];
  const float* W; unsigned short* Wt; int N;
  switch (z) {
    case 0:  W = WK;  Wt = (unsigned short*)(ws + WTK_OFF);  N = 1024; break;
    case 1:  W = WQ;  Wt = (unsigned short*)(ws + WTQ_OFF);  N = 1024; break;
    case 2:  W = WG1; Wt = (unsigned short*)(ws + WTG1_OFF); N = 1024; break;
    case 3:  W = WG2; Wt = (unsigned short*)(ws + WTG2_OFF); N = 1024; break;
    default: W = WV;  Wt = (unsigned short*)(ws + WTV_OFF);  N = 512;  break;
  }
  int n0 = blockIdx.x * 32, k0 = blockIdx.y * 32;
  if (n0 >= N) return;
  int kk = tid >> 3, nn = (tid & 7) * 4;
  float4 v = *(const float4*)(W + (size_t)(k0 + kk) * N + n0 + nn);
  T[kk][nn] = v.x; T[kk][nn + 1] = v.y; T[kk][nn + 2] = v.z; T[kk][nn + 3] = v.w;
  __syncthreads();
  int n2 = tid >> 3, k2 = (tid & 7) * 4;
  uint2 pw;
  pw.x = pack2(T[k2][n2],     T[k2 + 1][n2]);
  pw.y = pack2(T[k2 + 2][n2], T[k2 + 3][n2]);
  *(uint2*)(Wt + (size_t)(n0 + n2) * 512 + k0 + k2) = pw;
}

// Batched MFMA projection GEMM v2 (m97 structure, verified round 8).
__global__ __launch_bounds__(256)
void proj_mfma_kernel(const float* __restrict__ bKp, const float* __restrict__ bQp,
                      const float* __restrict__ bG1p, const float* __restrict__ bG2p,
                      const float* __restrict__ bVp, bf16* __restrict__ ws)
{
  __shared__ short As[128][64];
  __shared__ short Bs[128][64];
  const bf16* X; const bf16* Wt; const float* bias; unsigned short* C;
  int N; bool trans = false;
  switch (blockIdx.z) {
    case 0:  X = ws + XFA_OFF; Wt = ws + WTK_OFF;  bias = bKp;  C = (unsigned short*)(ws + KB_OFF); N = 1024; break;
    case 1:  X = ws + XSA_OFF; Wt = ws + WTQ_OFF;  bias = bQp;  C = (unsigned short*)(ws + QB_OFF); N = 1024; break;
    case 2:  X = ws + XFP_OFF; Wt = ws + WTG1_OFF; bias = bG1p; C = (unsigned short*)(ws + G1_OFF); N = 1024; break;
    case 3:  X = ws + XSP_OFF; Wt = ws + WTG2_OFF; bias = bG2p; C = (unsigned short*)(ws + G2_OFF); N = 1024; break;
    default: X = ws + XFA_OFF; Wt = ws + WTV_OFF;  bias = bVp;  C = (unsigned short*)(ws + VT_OFF); N = 512; trans = true; break;
  }
  const int n0 = blockIdx.x * 128;
  if (n0 >= N) return;
  const int m0 = blockIdx.y * 128;
  const int tid = threadIdx.x;
  const int w = tid >> 6, l = tid & 63, l15 = l & 15, l4 = l >> 4;
  const int wm = (w & 1) * 64, wn = (w >> 1) * 64;

  const int lr = l >> 3;
  const int cp = (l & 7) ^ lr;
  const bf16* gA = X  + (size_t)(m0 + w * 32 + lr) * 512 + cp * 8;
  const bf16* gB = Wt + (size_t)(n0 + w * 32 + lr) * 512 + cp * 8;
  char* const ldsA = (char*)&As[0][0] + w * 32 * 128;
  char* const ldsB = (char*)&Bs[0][0] + w * 32 * 128;

  const f32x4 zero = {0.f, 0.f, 0.f, 0.f};
  f32x4 acc[4][4];
#pragma unroll
  for (int i = 0; i < 4; ++i)
#pragma unroll
    for (int j = 0; j < 4; ++j) acc[i][j] = zero;

  const int swz = (l15 & 7) << 4;   // read-side XOR (row&7 == l15&7 here)

  for (int kc = 0; kc < 512; kc += 64) {
    __syncthreads();
#pragma unroll
    for (int i = 0; i < 4; ++i) {
      LOADLDS(gA + (size_t)i * 8 * 512 + kc, ldsA + i * 1024);
      LOADLDS(gB + (size_t)i * 8 * 512 + kc, ldsB + i * 1024);
    }
    __syncthreads();

#pragma unroll
    for (int kk = 0; kk < 2; ++kk) {
      short8 xf[4], wf[4];
#pragma unroll
      for (int t = 0; t < 4; ++t) {
        xf[t] = *(const short8*)((char*)&As[0][0] + (wm + t * 16 + l15) * 128
                                  + ((kk * 64 + l4 * 16) ^ swz));
        wf[t] = *(const short8*)((char*)&Bs[0][0] + (wn + t * 16 + l15) * 128
                                  + ((kk * 64 + l4 * 16) ^ swz));
      }
      if (!trans) {
#pragma unroll
        for (int i = 0; i < 4; ++i)
#pragma unroll
          for (int j = 0; j < 4; ++j)
            acc[i][j] = MFMA(wf[i], xf[j], acc[i][j]);   // D[n][m]
      } else {
#pragma unroll
        for (int i = 0; i < 4; ++i)
#pragma unroll
          for (int j = 0; j < 4; ++j)
            acc[i][j] = MFMA(xf[i], wf[j], acc[i][j]);   // D[m][n]
      }
    }
  }

  if (!trans) {
#pragma unroll
    for (int tn = 0; tn < 4; ++tn) {
      float4 b4 = *(const float4*)(bias + n0 + wn + tn * 16 + l4 * 4);
#pragma unroll
      for (int tm = 0; tm < 4; ++tm) {
        uint2 pw;
        pw.x = pack2(acc[tn][tm][0] + b4.x, acc[tn][tm][1] + b4.y);
        pw.y = pack2(acc[tn][tm][2] + b4.z, acc[tn][tm][3] + b4.w);
        *(uint2*)(C + (size_t)(m0 + wm + tm * 16 + l15) * N + n0 + wn + tn * 16 + l4 * 4) = pw;
      }
    }
  } else {
#pragma unroll
    for (int tn = 0; tn < 4; ++tn) {
      float bn = bias[n0 + wn + tn * 16 + l15];
#pragma unroll
      for (int tm = 0; tm < 4; ++tm) {
        uint2 pw;
        pw.x = pack2(acc[tm][tn][0] + bn, acc[tm][tn][1] + bn);
        pw.y = pack2(acc[tm][tn][2] + bn, acc[tm][tn][3] + bn);
        *(uint2*)(C + (size_t)(n0 + wn + tn * 16 + l15) * 2048 + m0 + wm + tm * 16 + l4 * 4) = pw;
      }
    }
  }
}

// MFMA fused attention, 8-wave (512-thread) blocks: 2 m-tiles share one staged
// K/G1/V copy -> staging instrs & barriers PER OUTPUT halved; 2 blocks/CU x 8
// waves = 16 waves/CU. Per-wave compute (scores -> P -> PV) identical to the
// round-8 kernel. V column-sum folded in. == ROUND-9 VERIFIED KERNEL (44.5us).
// r10's score-read-dedup (2 m-subs/wave) REVERTED: +32 VGPR Q/G2 doesn't fit
// the 128 cap at 2 blocks/CU -> scratch spill (FETCH 260MB, 136us). Third
// failed attempt at this lever (r3, r6, r10) -- closed.
__global__ __launch_bounds__(512)
void attn_mfma_kernel(const bf16* __restrict__ Kb, const bf16* __restrict__ G1b,
                      const bf16* __restrict__ Vtg, const bf16* __restrict__ Qb,
                      const bf16* __restrict__ G2b, bf16* __restrict__ ws)
{
  __shared__ short Ks[64][128];
  __shared__ short G1s[64][128];
  __shared__ short Vts[64][64];
  __shared__ short Ps[8][16][64];

  const int tid = threadIdx.x;
  const int w   = tid >> 6;        // 0..7
  const int wsb = w & 3;           // wave's m-sub within its tile
  const int mt  = w >> 2;          // which of the 2 m-tiles
  const int l   = tid & 63;
  const int l15 = l & 15;
  const int l4  = l >> 4;

  // XCD-aware remap: grid (16,8,4) -> f in [0,512); f%8 = XCD. vid=(f&7)*64+
  // (f>>3): XCD x gets vids [64x,64x+64) = head x, splits 0..3, all 16 m-blocks.
  const int f = blockIdx.x + blockIdx.y * 16 + blockIdx.z * 128;
  const int vid = (f & 7) * 64 + (f >> 3);
  const int m0    = (vid & 15) * 128;
  const int grp   = vid >> 4;      // 0..31
  const int h     = grp >> 2;
  const int split = grp & 3;
  const int mrow0 = m0 + mt * 64;  // this wave-group's 64-row m-tile

  short8 qf[4], gf[4];
  {
    const size_t ro = (size_t)(mrow0 + wsb * 16 + l15) * 1024 + h * 128 + l4 * 8;
#pragma unroll
    for (int kk = 0; kk < 4; ++kk) {
      qf[kk] = *(const short8*)(Qb + ro + kk * 32);
      gf[kk] = *(const short8*)(G2b + ro + kk * 32);
    }
  }
  float sc;
  {
    float sq = 0.f, sg = 0.f;
#pragma unroll
    for (int kk = 0; kk < 4; ++kk)
#pragma unroll
      for (int j = 0; j < 8; ++j) {
        float q = b2f((unsigned short)qf[kk][j]);
        float g = b2f((unsigned short)gf[kk][j]);
        sq += q * q; sg += g * g;
      }
    sq += __shfl_xor(sq, 16, 64); sq += __shfl_xor(sq, 32, 64);
    sg += __shfl_xor(sg, 16, 64); sg += __shfl_xor(sg, 32, 64);
    sc = rsqrtf(sq) * rsqrtf(sg) * (1.0f / 16384.0f);   // per-lane m-row scale
  }

  // staging: 512 threads cover each tile exactly once.
  const int r0  = tid >> 3;          // 0..63  K/G row
  const int c0  = (tid & 7) * 16;    // shorts
  const int c0b = c0 * 2;            // bytes
  const int jv  = tid >> 3;          // 0..63  V row (dv)
  const int nv  = (tid & 7) * 8;     // shorts
  const int nvB = nv * 2;            // bytes

  short8 pk0, pk1, pg0, pg1, pv0;
  auto load_tile = [&](int nt) {     // nt in global 64-units
    const int n0 = nt * 64;
    const bf16* kp = Kb  + (size_t)(n0 + r0) * 1024 + h * 128 + c0;
    const bf16* gp = G1b + (size_t)(n0 + r0) * 1024 + h * 128 + c0;
    pk0 = *(const short8*)(kp);
    pk1 = *(const short8*)(kp + 8);
    pg0 = *(const short8*)(gp);
    pg1 = *(const short8*)(gp + 8);
    const bf16* vp = Vtg + (size_t)(h * 64 + jv) * 2048 + n0 + nv;
    pv0 = *(const short8*)(vp);
  };
  const int ntbase = split * 8;
  load_tile(ntbase);

  const f32x4 zero = {0.f, 0.f, 0.f, 0.f};
  f32x4 accO[4], accD = zero;
#pragma unroll
  for (int t = 0; t < 4; ++t) accO[t] = zero;
  float vsum_part = 0.f;

  short8 ones;
#pragma unroll
  for (int j = 0; j < 8; ++j) ones[j] = (short)0x3F80;

  char* const ksb = (char*)&Ks[0][0];
  char* const g1p = (char*)&G1s[0][0];
  char* const vsb = (char*)&Vts[0][0];
  char* const psb = (char*)&Ps[w][0][0];

  for (int nt = 0; nt < 8; ++nt) {
    __syncthreads();
    *(short8*)(ksb + KSWZ(r0, c0b))      = pk0;
    *(short8*)(ksb + KSWZ(r0, c0b + 16)) = pk1;
    *(short8*)(g1p + KSWZ(r0, c0b))      = pg0;
    *(short8*)(g1p + KSWZ(r0, c0b + 16)) = pg1;
    *(short8*)(vsb + VSWZ(jv, nvB))      = pv0;
#pragma unroll
    for (int j = 0; j < 8; ++j)          // V col-sum partial (this split's n)
      vsum_part += b2f((unsigned short)pv0[j]);
    __syncthreads();
    if (nt + 1 < 8) load_tile(ntbase + nt + 1);

    // scores: swapped operands -> lane holds S[n-quads][m=l15] (wave-private)
#pragma unroll
    for (int t = 0; t < 4; ++t) {
      f32x4 sa = zero, sg2 = zero;
      __builtin_amdgcn_s_setprio(1);
#pragma unroll
      for (int kk = 0; kk < 4; ++kk) {
        short8 kbf = *(const short8*)(ksb + KSWZ(t * 16 + l15, kk * 64 + l4 * 16));
        sa  = MFMA(kbf, qf[kk], sa);
        short8 gbf = *(const short8*)(g1p + KSWZ(t * 16 + l15, kk * 64 + l4 * 16));
        sg2 = MFMA(gbf, gf[kk], sg2);
      }
      __builtin_amdgcn_s_setprio(0);
      // P' = exp(x)-1 ~= x + x^2/2 (|x| ~ 1e-4)
      float x0 = sa[0] * sg2[0] * sc;
      float x1 = sa[1] * sg2[1] * sc;
      float x2 = sa[2] * sg2[2] * sc;
      float x3 = sa[3] * sg2[3] * sc;
      float p0 = __builtin_fmaf(0.5f * x0, x0, x0);
      float p1 = __builtin_fmaf(0.5f * x1, x1, x1);
      float p2 = __builtin_fmaf(0.5f * x2, x2, x2);
      float p3 = __builtin_fmaf(0.5f * x3, x3, x3);
      uint2 pw;
      pw.x = pack_bf2(p0, p1);
      pw.y = pack_bf2(p2, p3);
      *(uint2*)(psb + PSWZ(l15, t * 32 + l4 * 8)) = pw;
    }

    // PV + denominator from swizzled LDS V tile
#pragma unroll
    for (int ks = 0; ks < 2; ++ks) {
      short8 pf = *(const short8*)(psb + PSWZ(l15, ks * 64 + l4 * 16));
      __builtin_amdgcn_s_setprio(1);
      accD = MFMA(pf, ones, accD);
#pragma unroll
      for (int jt = 0; jt < 4; ++jt) {
        short8 vbf = *(const short8*)(vsb + VSWZ(jt * 16 + l15, ks * 64 + l4 * 16));
        accO[jt] = MFMA(pf, vbf, accO[jt]);
      }
      __builtin_amdgcn_s_setprio(0);
    }
  }

  // ---- vsum reduce: 8 consecutive lanes (same jv) hold quarters of row jv ----
  vsum_part += __shfl_xor(vsum_part, 1, 64);
  vsum_part += __shfl_xor(vsum_part, 2, 64);
  vsum_part += __shfl_xor(vsum_part, 4, 64);
  if ((vid & 15) == 0 && (tid & 7) == 0)
    ((float*)(ws + VSUM_OFF))[(size_t)(split * 8 + h) * 64 + jv] = vsum_part;

  // ---- write partials ----
  size_t noff;
  switch (split) {
    case 0:  noff = NUM0_OFF; break;
    case 1:  noff = NUM1_OFF; break;
    case 2:  noff = NUM2_OFF; break;
    default: noff = NUM3_OFF; break;
  }
  bf16* num = ws + noff;
  float* den = (float*)(ws + DEN_OFF);
  if (l15 == 0) {
#pragma unroll
    for (int r = 0; r < 4; ++r)
      den[(size_t)(split * 8 + h) * 2048 + mrow0 + wsb * 16 + l4 * 4 + r] = accD[r];
  }
#pragma unroll
  for (int jt = 0; jt < 4; ++jt) {
#pragma unroll
    for (int r = 0; r < 4; ++r)
      num[(size_t)(mrow0 + wsb * 16 + l4 * 4 + r) * 512 + h * 64 + jt * 16 + l15]
        = __float2bfloat16(accO[jt][r]);
  }
}

// out[m][c] = (num0..3 + Vsum[c]) / (2048 + den0..3), 8 elems/thread
__global__ __launch_bounds__(256)
void combine_kernel(const bf16* __restrict__ ws, float* __restrict__ out)
{
  const unsigned short* num0 = (const unsigned short*)(ws + NUM0_OFF);
  const unsigned short* num1 = (const unsigned short*)(ws + NUM1_OFF);
  const unsigned short* num2 = (const unsigned short*)(ws + NUM2_OFF);
  const unsigned short* num3 = (const unsigned short*)(ws + NUM3_OFF);
  const float* den  = (const float*)(ws + DEN_OFF);
  const float* vsum = (const float*)(ws + VSUM_OFF);   // f32 [4][8][64]
  int idx = (blockIdx.x * 256 + threadIdx.x) * 8;
  int m = idx >> 9, c = idx & 511, h = c >> 6, c64 = c & 63;
  float d = 2048.0f + den[(size_t)h * 2048 + m] + den[(size_t)(8 + h) * 2048 + m]
                    + den[(size_t)(16 + h) * 2048 + m] + den[(size_t)(24 + h) * 2048 + m];
  float rd = 1.0f / d;
  short8 a = *(const short8*)(num0 + idx);
  short8 b = *(const short8*)(num1 + idx);
  short8 e = *(const short8*)(num2 + idx);
  short8 g = *(const short8*)(num3 + idx);
  float vs[8] = {0.f, 0.f, 0.f, 0.f, 0.f, 0.f, 0.f, 0.f};
#pragma unroll
  for (int s = 0; s < 4; ++s) {
    float4 v0 = *(const float4*)(vsum + (size_t)(s * 8 + h) * 64 + c64);
    float4 v1 = *(const float4*)(vsum + (size_t)(s * 8 + h) * 64 + c64 + 4);
    vs[0] += v0.x; vs[1] += v0.y; vs[2] += v0.z; vs[3] += v0.w;
    vs[4] += v1.x; vs[5] += v1.y; vs[6] += v1.z; vs[7] += v1.w;
  }
  float r[8];
#pragma unroll
  for (int j = 0; j < 8; ++j)
    r[j] = (b2f((unsigned short)a[j]) + b2f((unsigned short)b[j])
          + b2f((unsigned short)e[j]) + b2f((unsigned short)g[j]) + vs[j]) * rd;
  *(float4*)(out + idx)     = float4{r[0], r[1], r[2], r[3]};
  *(float4*)(out + idx + 4) = float4{r[4], r[5], r[6], r[7]};
}

extern "C" void kernel_launch(void* const* d_in, const int* in_sizes, int n_in,
                              void* d_out, int out_size, void* d_ws, size_t ws_size,
                              hipStream_t stream) {
  const float* first_app  = (const float*)d_in[0];
  const float* first_pos  = (const float*)d_in[1];
  const float* second_app = (const float*)d_in[2];
  const float* second_pos = (const float*)d_in[3];
  const float* WK  = (const float*)d_in[4];
  const float* bK  = (const float*)d_in[5];
  const float* WQ  = (const float*)d_in[6];
  const float* bQ  = (const float*)d_in[7];
  const float* WV  = (const float*)d_in[8];
  const float* bV  = (const float*)d_in[9];
  const float* WG1 = (const float*)d_in[10];
  const float* bG1 = (const float*)d_in[11];
  const float* WG2 = (const float*)d_in[12];
  const float* bG2 = (const float*)d_in[13];

  bf16* ws = (bf16*)d_ws;

  prep_kernel<<<dim3(32, 16, 9), 256, 0, stream>>>(
      WK, WQ, WG1, WG2, WV, first_app, first_pos, second_app, second_pos, ws);
  proj_mfma_kernel<<<dim3(8, 16, 5), 256, 0, stream>>>(bK, bQ, bG1, bG2, bV, ws);
  attn_mfma_kernel<<<dim3(16, 8, 4), 512, 0, stream>>>(
      ws + KB_OFF, ws + G1_OFF, ws + VT_OFF, ws + QB_OFF, ws + G2_OFF, ws);
  combine_kernel<<<dim3(512), 256, 0, stream>>>(ws, (float*)d_out);
}